// Round 17
// baseline (63.266 us; speedup 1.0000x reference)
//
#include <hip/hip_runtime.h>
#include <hip/hip_bf16.h>
#include <math.h>

#define NSP 4096      // h*w*z = 16^3
#define CD 128        // channels
#define NB 2          // batch
#define NH 4          // heads
#define JS 4          // j-splits in attention
#define JSTEP 64
#define NSTEP ((NSP / JS) / JSTEP)   // 16

typedef __attribute__((ext_vector_type(8))) short bf16x8;   // 8 bf16 (4 VGPRs)
typedef __attribute__((ext_vector_type(4))) float f32x4;

static constexpr float QSCALE = 10.0f * 1.4426950408889634f;  // scale * log2(e)

__device__ __forceinline__ ushort f2bf(float f) {
    union { float f; unsigned u; } v; v.f = f;
    unsigned r = v.u + 0x7fffu + ((v.u >> 16) & 1u);   // RNE, finite inputs only
    return (ushort)(r >> 16);
}
__device__ __forceinline__ float bf2f(ushort u) {
    union { unsigned u; float f; } v; v.u = ((unsigned)u) << 16;
    return v.f;
}
// RNE pack via compiler builtin (v_cvt_pk_bf16_f32): low16=a, high16=b
__device__ __forceinline__ unsigned pk2bf(float a, float b) {
    union { __hip_bfloat162 h; unsigned u; } t;
    t.h = __float22bfloat162_rn(make_float2(a, b));
    return t.u;
}
__device__ __forceinline__ void gload_lds16(const void* g, void* l) {
    __builtin_amdgcn_global_load_lds(
        (const __attribute__((address_space(1))) unsigned int*)g,
        (__attribute__((address_space(3))) unsigned int*)l, 16, 0, 0);
}
// load 8 fp32 weights and pack to a bf16x8 fragment (RNE, same bits as f2bf)
__device__ __forceinline__ bf16x8 wfrag(const float* p) {
    const float4 a = *(const float4*)(p);
    const float4 b = *(const float4*)(p + 4);
    union { unsigned u[4]; bf16x8 v; } o;
    o.u[0] = pk2bf(a.x, a.y);
    o.u[1] = pk2bf(a.z, a.w);
    o.u[2] = pk2bf(b.x, b.y);
    o.u[3] = pk2bf(b.z, b.w);
    return o.v;
}

// ---------------- MFMA q,k,v projection (direct fp32 inputs, in-kernel transpose) ----
// grid 512 (b*256 + xblk). Per block: 16 n, all 128 o. Qt/Kt chunk-major raw bf16.
__global__ __launch_bounds__(256) void proj_qkv_mfma(
    const float* __restrict__ x, const float* __restrict__ cx,
    const float* __restrict__ WqF, const float* __restrict__ WkF, const float* __restrict__ WvF,
    const float* __restrict__ Bq, const float* __restrict__ Bk, const float* __restrict__ Bv,
    ushort* __restrict__ Qt, ushort* __restrict__ Kt, ushort* __restrict__ V16,
    float* __restrict__ partQ, float* __restrict__ partK)
{
    __shared__ __align__(16) ushort Xl[16][128];
    __shared__ __align__(16) ushort Cl[16][128];
    const int t = threadIdx.x;
    const int wid = t >> 6, lane = t & 63;
    const int g = lane >> 4, n16 = lane & 15;
    const int nt = blockIdx.x;
    const int b  = nt >> 8;
    const int xblk = nt & 255;
    const int nb = xblk * 16;

    // load + cast + transpose: x/cx [128 c][16 n] fp32 -> LDS [16 n][128 c] bf16,
    // column chunk swizzled: element c stored at chunk (c>>3)^(n&7)
    {
        const int c = t >> 1, half = t & 1;
        const float* xs = x  + ((size_t)b * CD + c) * NSP + nb + half * 8;
        const float* cs = cx + ((size_t)b * CD + c) * NSP + nb + half * 8;
        float xv[8], cv[8];
        *(float4*)(xv)     = *(const float4*)(xs);
        *(float4*)(xv + 4) = *(const float4*)(xs + 4);
        *(float4*)(cv)     = *(const float4*)(cs);
        *(float4*)(cv + 4) = *(const float4*)(cs + 4);
        const int c8 = c >> 3, ce = c & 7;
        #pragma unroll
        for (int j = 0; j < 8; ++j) {
            const int n = half * 8 + j;
            const int col = ((c8 ^ (n & 7)) << 3) + ce;
            Xl[n][col] = f2bf(xv[j]);
            Cl[n][col] = f2bf(cv[j]);
        }
    }
    __syncthreads();

    bf16x8 bx[4], bc[4];
    #pragma unroll
    for (int ks = 0; ks < 4; ++ks) {
        const int col = (((4 * ks + g) ^ (n16 & 7)) << 3);
        bx[ks] = *(const bf16x8*)(&Xl[n16][col]);
        bc[ks] = *(const bf16x8*)(&Cl[n16][col]);
    }
    const int jb = nb >> 6, jr = (nb & 63) + n16;

    #pragma unroll
    for (int hf = 0; hf < 2; ++hf) {
        const int o0 = hf * 64 + wid * 16;
        const size_t wrow = (size_t)(o0 + n16) * CD;

        f32x4 aq = {0,0,0,0}, ak = {0,0,0,0}, av = {0,0,0,0};
        #pragma unroll
        for (int ks = 0; ks < 4; ++ks) {
            const int k0 = ks * 32 + g * 8;
            const bf16x8 wqf = wfrag(WqF + wrow + k0);
            const bf16x8 wkf = wfrag(WkF + wrow + k0);
            const bf16x8 wvf = wfrag(WvF + wrow + k0);
            aq = __builtin_amdgcn_mfma_f32_16x16x32_bf16(wqf, bx[ks], aq, 0, 0, 0);
            ak = __builtin_amdgcn_mfma_f32_16x16x32_bf16(wkf, bc[ks], ak, 0, 0, 0);
            av = __builtin_amdgcn_mfma_f32_16x16x32_bf16(wvf, bc[ks], av, 0, 0, 0);
        }
        float qv[4], kv[4], sq[4], sk[4];
        #pragma unroll
        for (int r = 0; r < 4; ++r) {
            const int o = o0 + 4 * g + r;
            qv[r] = aq[r] + Bq[o];
            kv[r] = ak[r] + Bk[o];
            V16[((size_t)(b * CD + o)) * NSP + nb + n16] = f2bf(av[r] + Bv[o]);
            sq[r] = qv[r] * qv[r]; sk[r] = kv[r] * kv[r];
        }
        {
            const int o_first = o0 + 4 * g;
            const int bh = b * NH + (o_first >> 5);
            const int chunk = ((o_first & 31) >> 3);
            const size_t idx = (((size_t)(bh * 64 + jb)) * 4 + chunk) * 512
                             + (size_t)jr * 8 + 4 * (g & 1);
            uint2 qs, ks2;
            qs.x  = pk2bf(qv[0], qv[1]); qs.y  = pk2bf(qv[2], qv[3]);
            ks2.x = pk2bf(kv[0], kv[1]); ks2.y = pk2bf(kv[2], kv[3]);
            *(uint2*)(Qt + idx) = qs;
            *(uint2*)(Kt + idx) = ks2;
        }
        #pragma unroll
        for (int r = 0; r < 4; ++r) {
            #pragma unroll
            for (int off = 1; off < 16; off <<= 1) {
                sq[r] += __shfl_xor(sq[r], off);
                sk[r] += __shfl_xor(sk[r], off);
            }
        }
        if (n16 == 0) {
            #pragma unroll
            for (int r = 0; r < 4; ++r) {
                const int ch = b * CD + o0 + 4 * g + r;
                partQ[(size_t)ch * 256 + xblk] = sq[r];
                partK[(size_t)ch * 256 + xblk] = sk[r];
            }
        }
    }
}

// ---------------- reduce norm partials -> combined per-channel factor ----------------
__global__ __launch_bounds__(256) void normfin(
    const float* __restrict__ partQ, const float* __restrict__ partK,
    float* __restrict__ fsc)
{
    const int ch = blockIdx.x;
    const int t = threadIdx.x;
    float vq = partQ[(size_t)ch * 256 + t];
    float vk = partK[(size_t)ch * 256 + t];
    #pragma unroll
    for (int off = 32; off > 0; off >>= 1) {
        vq += __shfl_down(vq, off, 64);
        vk += __shfl_down(vk, off, 64);
    }
    __shared__ float redq[4], redk[4];
    if ((t & 63) == 0) { redq[t >> 6] = vq; redk[t >> 6] = vk; }
    __syncthreads();
    if (t == 0) {
        const float nq = sqrtf(redq[0] + redq[1] + redq[2] + redq[3]);
        const float nk = sqrtf(redk[0] + redk[1] + redk[2] + redk[3]);
        fsc[ch] = QSCALE / (fmaxf(nq, 1e-12f) * fmaxf(nk, 1e-12f));
    }
}

// ---------------- MFMA flash attention partials (phase-batched) ----------------
// grid 1024, 4 waves, 32 q/wave. 4-buffer K/V rotation, counted vmcnt.
__global__ __launch_bounds__(256, 4) void attn_mfma(
    const ushort* __restrict__ Qt, const ushort* __restrict__ Kt,
    const ushort* __restrict__ V16, const float* __restrict__ fsc,
    unsigned* __restrict__ pacc, float* __restrict__ pl)
{
    __shared__ __align__(16) ushort Kl[4][2048];   // 16KB
    __shared__ __align__(16) ushort Vl[4][2048];   // 16KB

    const int t = threadIdx.x;
    const int wid = t >> 6, lane = t & 63;
    const int g = lane >> 4, n16 = lane & 15;
    const int f = blockIdx.x;
    const int bh = f & 7, it32 = (f >> 3) & 31, js = f >> 8;
    const int b = bh >> 2, h = bh & 3;
    const int i0 = it32 * 128 + wid * 32;

    const ushort* QtB = Qt + (size_t)bh * NSP * 32;
    const ushort* KtB = Kt + (size_t)bh * NSP * 32;
    const ushort* Vb  = V16 + (size_t)(b * CD + h * 32) * NSP;

    const float* fb = fsc + b * CD + h * 32 + g * 8;
    const f32x4 fA = *(const f32x4*)(fb);
    const f32x4 fB = *(const f32x4*)(fb + 4);

    const size_t qoff = ((size_t)(i0 >> 6) * 4 + g) * 512 + (size_t)(i0 & 63) * 8;
    const bf16x8 qr0 = *(const bf16x8*)(QtB + qoff + n16 * 8);
    const bf16x8 qr1 = *(const bf16x8*)(QtB + qoff + (16 + n16) * 8);
    auto scaleq = [&](bf16x8 q) -> bf16x8 {
        union { unsigned u[4]; bf16x8 v; } o;
        o.u[0] = pk2bf(bf2f((ushort)q[0]) * fA.x, bf2f((ushort)q[1]) * fA.y);
        o.u[1] = pk2bf(bf2f((ushort)q[2]) * fA.z, bf2f((ushort)q[3]) * fA.w);
        o.u[2] = pk2bf(bf2f((ushort)q[4]) * fB.x, bf2f((ushort)q[5]) * fB.y);
        o.u[3] = pk2bf(bf2f((ushort)q[6]) * fB.z, bf2f((ushort)q[7]) * fB.w);
        return o.v;
    };
    const bf16x8 qf[2] = { scaleq(qr0), scaleq(qr1) };

    f32x4 acc[2][2] = {{{0,0,0,0},{0,0,0,0}},{{0,0,0,0},{0,0,0,0}}};
    float l0 = 0.f, l1 = 0.f;
    const f32x4 zero = {0,0,0,0};

    const int klp = lane ^ (wid * 2);               // K source permute
    const int vd  = wid * 8 + (lane >> 3);          // V row this lane stages
    const int vsw = (lane & 7) ^ (lane >> 3);       // V 16B-chunk XOR swizzle
    auto stageK = [&](int buf, int jt) {
        gload_lds16(KtB + ((size_t)(jt >> 6) * 4 + wid) * 512 + klp * 8,
                    &Kl[buf][wid * 512]);
    };
    auto stageV = [&](int buf, int jt) {
        gload_lds16(Vb + (size_t)vd * NSP + jt + vsw * 8, &Vl[buf][wid * 512]);
    };

    const int jbeg = js * (NSP / JS);
    stageK(0, jbeg);          stageV(0, jbeg);
    stageK(1, jbeg + JSTEP);  stageV(1, jbeg + JSTEP);

    for (int step = 0; step < NSTEP; ++step) {
        const int jt = jbeg + step * JSTEP;
        if (step + 2 < NSTEP) {
            stageK((step + 2) & 3, jt + 2 * JSTEP);
            stageV((step + 2) & 3, jt + 2 * JSTEP);
            asm volatile("s_waitcnt vmcnt(4)" ::: "memory");
        } else if (step + 1 < NSTEP) {
            asm volatile("s_waitcnt vmcnt(2)" ::: "memory");
        } else {
            asm volatile("s_waitcnt vmcnt(0)" ::: "memory");
        }
        __builtin_amdgcn_s_barrier();
        const int cur = step & 3;
        __builtin_amdgcn_s_setprio(1);

        // ---- phase A: all LDS reads + all 8 QK MFMAs ----
        bf16x8 kf[2][2];
        union { uint2 u2[2]; bf16x8 v; } vf[2][2];
        #pragma unroll
        for (int s = 0; s < 2; ++s) {
            kf[s][0] = *(const bf16x8*)(&Kl[cur][g * 512 + ((s * 32 + n16) ^ (g * 2)) * 8]);
            kf[s][1] = *(const bf16x8*)(&Kl[cur][g * 512 + ((s * 32 + 16 + n16) ^ (g * 2)) * 8]);
            const int c0 = ((4 * s + (g >> 1)) ^ (n16 & 7)) * 8 + (g & 1) * 4;
            const int c1 = ((4 * s + 2 + (g >> 1)) ^ (n16 & 7)) * 8 + (g & 1) * 4;
            vf[s][0].u2[0] = *(const uint2*)(&Vl[cur][n16 * 64 + c0]);
            vf[s][0].u2[1] = *(const uint2*)(&Vl[cur][n16 * 64 + c1]);
            vf[s][1].u2[0] = *(const uint2*)(&Vl[cur][(16 + n16) * 64 + c0]);
            vf[s][1].u2[1] = *(const uint2*)(&Vl[cur][(16 + n16) * 64 + c1]);
        }
        f32x4 sv[2][2][2];
        #pragma unroll
        for (int s = 0; s < 2; ++s)
            #pragma unroll
            for (int it = 0; it < 2; ++it) {
                sv[s][it][0] = __builtin_amdgcn_mfma_f32_16x16x32_bf16(kf[s][0], qf[it], zero, 0, 0, 0);
                sv[s][it][1] = __builtin_amdgcn_mfma_f32_16x16x32_bf16(kf[s][1], qf[it], zero, 0, 0, 0);
            }

        // ---- phase B: softmax numerators ----
        union { unsigned u[4]; bf16x8 v; } pf[2][2];
        #pragma unroll
        for (int s = 0; s < 2; ++s)
            #pragma unroll
            for (int it = 0; it < 2; ++it) {
                const f32x4 s0 = sv[s][it][0], s1 = sv[s][it][1];
                const float p0 = __builtin_amdgcn_exp2f(s0.x);
                const float p1 = __builtin_amdgcn_exp2f(s0.y);
                const float p2 = __builtin_amdgcn_exp2f(s0.z);
                const float p3 = __builtin_amdgcn_exp2f(s0.w);
                const float p4 = __builtin_amdgcn_exp2f(s1.x);
                const float p5 = __builtin_amdgcn_exp2f(s1.y);
                const float p6 = __builtin_amdgcn_exp2f(s1.z);
                const float p7 = __builtin_amdgcn_exp2f(s1.w);
                const float ps = ((p0 + p1) + (p2 + p3)) + ((p4 + p5) + (p6 + p7));
                if (it) l1 += ps; else l0 += ps;
                pf[s][it].u[0] = pk2bf(p0, p1);
                pf[s][it].u[1] = pk2bf(p2, p3);
                pf[s][it].u[2] = pk2bf(p4, p5);
                pf[s][it].u[3] = pk2bf(p6, p7);
            }

        // ---- phase C: all 8 PV MFMAs ----
        #pragma unroll
        for (int s = 0; s < 2; ++s)
            #pragma unroll
            for (int it = 0; it < 2; ++it) {
                acc[it][0] = __builtin_amdgcn_mfma_f32_16x16x32_bf16(vf[s][0].v, pf[s][it].v, acc[it][0], 0, 0, 0);
                acc[it][1] = __builtin_amdgcn_mfma_f32_16x16x32_bf16(vf[s][1].v, pf[s][it].v, acc[it][1], 0, 0, 0);
            }
        __builtin_amdgcn_s_setprio(0);
    }

    l0 += __shfl_xor(l0, 16); l0 += __shfl_xor(l0, 32);
    l1 += __shfl_xor(l1, 16); l1 += __shfl_xor(l1, 32);

    const size_t base = (size_t)js * 8 + bh;
    if (lane < 16) {
        pl[base * NSP + i0 + n16]      = l0;
        pl[base * NSP + i0 + 16 + n16] = l1;
    }
    unsigned* pb = pacc + base * 16 * NSP;
    const int col0 = i0 + n16, col1 = i0 + 16 + n16;
    pb[(size_t)(2 * g)     * NSP + col0] = pk2bf(acc[0][0][0], acc[0][0][1]);
    pb[(size_t)(2 * g + 1) * NSP + col0] = pk2bf(acc[0][0][2], acc[0][0][3]);
    pb[(size_t)(8 + 2 * g)     * NSP + col0] = pk2bf(acc[0][1][0], acc[0][1][1]);
    pb[(size_t)(8 + 2 * g + 1) * NSP + col0] = pk2bf(acc[0][1][2], acc[0][1][3]);
    pb[(size_t)(2 * g)     * NSP + col1] = pk2bf(acc[1][0][0], acc[1][0][1]);
    pb[(size_t)(2 * g + 1) * NSP + col1] = pk2bf(acc[1][0][2], acc[1][0][3]);
    pb[(size_t)(8 + 2 * g)     * NSP + col1] = pk2bf(acc[1][1][0], acc[1][1][1]);
    pb[(size_t)(8 + 2 * g + 1) * NSP + col1] = pk2bf(acc[1][1][2], acc[1][1][3]);
}

// ---------------- fused combine + output projection (fp32 Wo, in-register cast) -----
__global__ __launch_bounds__(256) void combine_proj_out(
    const unsigned* __restrict__ pacc, const float* __restrict__ pl,
    const float* __restrict__ WoF, const float* __restrict__ Bo,
    float* __restrict__ outp)
{
    __shared__ __align__(16) ushort Yl[16][128];
    const int t = threadIdx.x;
    const int nt = blockIdx.x;
    const int b  = nt >> 8;
    const int nb = (nt & 255) * 16;

    {
        const int nl = t & 15, hh = (t >> 4) & 3, q = t >> 6;
        const int bh = b * NH + hh;
        const int n = nb + nl;
        float L = 0.f;
        #pragma unroll
        for (int s = 0; s < JS; ++s) L += pl[((size_t)(s * 8 + bh)) * NSP + n];
        const float invL = 1.0f / L;
        unsigned u[4];
        #pragma unroll
        for (int e = 0; e < 4; ++e) {
            const int dp = q * 4 + e;
            float a0 = 0.f, a1 = 0.f;
            #pragma unroll
            for (int s = 0; s < JS; ++s) {
                const unsigned w = pacc[(((size_t)(s * 8 + bh)) * 16 + dp) * NSP + n];
                union { unsigned u; float f; } lo, hi;
                lo.u = w << 16; hi.u = w & 0xffff0000u;
                a0 += lo.f; a1 += hi.f;
            }
            u[e] = pk2bf(a0 * invL, a1 * invL);
        }
        const int chunk = hh * 4 + q;
        *(uint4*)(&Yl[nl][((chunk ^ (nl & 7)) * 8)]) = make_uint4(u[0], u[1], u[2], u[3]);
    }
    __syncthreads();

    const int wid = t >> 6, lane = t & 63;
    const int g = lane >> 4, n16 = lane & 15;
    #pragma unroll
    for (int half = 0; half < 2; ++half) {
        const int o0 = half * 64 + wid * 16;
        const size_t wrow = (size_t)(o0 + n16) * CD;
        f32x4 a = {0,0,0,0};
        #pragma unroll
        for (int ks = 0; ks < 4; ++ks) {
            const bf16x8 wf = wfrag(WoF + wrow + ks * 32 + g * 8);
            const int chunk = ks * 4 + g;
            const bf16x8 yf = *(const bf16x8*)(&Yl[n16][((chunk ^ (n16 & 7)) * 8)]);
            a = __builtin_amdgcn_mfma_f32_16x16x32_bf16(wf, yf, a, 0, 0, 0);
        }
        #pragma unroll
        for (int r = 0; r < 4; ++r) {
            const int o = o0 + 4 * g + r;
            outp[((size_t)(b * CD + o)) * NSP + nb + n16] = a[r] + Bo[o];
        }
    }
}

extern "C" void kernel_launch(void* const* d_in, const int* in_sizes, int n_in,
                              void* d_out, int out_size, void* d_ws, size_t ws_size,
                              hipStream_t stream)
{
    const float* x  = (const float*)d_in[0];
    const float* cx = (const float*)d_in[1];
    const float* Wq = (const float*)d_in[2];
    const float* bq = (const float*)d_in[3];
    const float* Wk = (const float*)d_in[4];
    const float* bk = (const float*)d_in[5];
    const float* Wv = (const float*)d_in[6];
    const float* bv = (const float*)d_in[7];
    const float* Wo = (const float*)d_in[8];
    const float* bo = (const float*)d_in[9];
    float* out = (float*)d_out;

    char* w = (char*)d_ws;
    float*   fsc  = (float*)w;   w += 4096;
    float*   partQ = (float*)w;  w += (size_t)NB * CD * 256 * 4;        // 256 KB
    float*   partK = (float*)w;  w += (size_t)NB * CD * 256 * 4;        // 256 KB
    ushort*  Qt   = (ushort*)w;  w += (size_t)NB * NH * NSP * 32 * 2;   // 2 MB
    ushort*  Kt   = (ushort*)w;  w += (size_t)NB * NH * NSP * 32 * 2;   // 2 MB
    ushort*  V16  = (ushort*)w;  w += (size_t)NB * CD * NSP * 2;        // 2 MB
    unsigned* pacc = (unsigned*)w; w += (size_t)JS * 8 * 16 * NSP * 4;  // 8 MB
    float*   pl   = (float*)w;                                          // 512 KB

    proj_qkv_mfma<<<dim3(512), 256, 0, stream>>>(x, cx, Wq, Wk, Wv, bq, bk, bv,
                                                 Qt, Kt, V16, partQ, partK);
    normfin<<<dim3(256), 256, 0, stream>>>(partQ, partK, fsc);
    attn_mfma<<<dim3(1024), 256, 0, stream>>>(Qt, Kt, V16, fsc, pacc, pl);
    combine_proj_out<<<dim3(512), 256, 0, stream>>>(pacc, pl, Wo, bo, out);
}

// Round 18
// 61.964 us; speedup vs baseline: 1.0210x; 1.0210x over previous
//
#include <hip/hip_runtime.h>
#include <hip/hip_bf16.h>
#include <math.h>

#define NSP 4096      // h*w*z = 16^3
#define CD 128        // channels
#define NB 2          // batch
#define NH 4          // heads
#define JS 4          // j-splits in attention
#define JSTEP 64
#define NSTEP ((NSP / JS) / JSTEP)   // 16

typedef __attribute__((ext_vector_type(8))) short bf16x8;   // 8 bf16 (4 VGPRs)
typedef __attribute__((ext_vector_type(4))) float f32x4;

static constexpr float QSCALE = 10.0f * 1.4426950408889634f;  // scale * log2(e)

__device__ __forceinline__ ushort f2bf(float f) {
    union { float f; unsigned u; } v; v.f = f;
    unsigned r = v.u + 0x7fffu + ((v.u >> 16) & 1u);   // RNE, finite inputs only
    return (ushort)(r >> 16);
}
__device__ __forceinline__ float bf2f(ushort u) {
    union { unsigned u; float f; } v; v.u = ((unsigned)u) << 16;
    return v.f;
}
// RNE pack via compiler builtin (v_cvt_pk_bf16_f32): low16=a, high16=b
__device__ __forceinline__ unsigned pk2bf(float a, float b) {
    union { __hip_bfloat162 h; unsigned u; } t;
    t.h = __float22bfloat162_rn(make_float2(a, b));
    return t.u;
}
__device__ __forceinline__ void gload_lds16(const void* g, void* l) {
    __builtin_amdgcn_global_load_lds(
        (const __attribute__((address_space(1))) unsigned int*)g,
        (__attribute__((address_space(3))) unsigned int*)l, 16, 0, 0);
}

// ---------------- fused cast: transpose x,cx -> bf16 [b][n][c]; weights -> bf16 ----
__global__ __launch_bounds__(256) void cast_all(
    const float* __restrict__ x, const float* __restrict__ cx,
    const float* __restrict__ Wq, const float* __restrict__ Wk,
    const float* __restrict__ Wv, const float* __restrict__ Wo,
    ushort* __restrict__ Xt, ushort* __restrict__ Ct, ushort* __restrict__ Wall)
{
    const int t = threadIdx.x;
    if (blockIdx.x >= 128) {
        const int sub = blockIdx.x - 128;                // 0..15
        const int m = blockIdx.z * 2 + blockIdx.y;       // 0..3
        const float* src = (m == 0) ? Wq : (m == 1) ? Wk : (m == 2) ? Wv : Wo;
        const int off = sub * 1024 + t * 4;
        const float4 v = *(const float4*)(src + off);
        ushort4 o;
        o.x = f2bf(v.x); o.y = f2bf(v.y); o.z = f2bf(v.z); o.w = f2bf(v.w);
        *(ushort4*)(Wall + m * 16384 + off) = o;
        return;
    }
    __shared__ ushort L[32][130];
    const int n0 = blockIdx.x * 32;
    const int b  = blockIdx.y;
    const float* in = (blockIdx.z == 0) ? x : cx;
    ushort* outp    = (blockIdx.z == 0) ? Xt : Ct;
    const int nl = t & 31, cq = t >> 5;
    #pragma unroll
    for (int cc = cq; cc < CD; cc += 8)
        L[nl][cc] = f2bf(in[((size_t)b * CD + cc) * NSP + n0 + nl]);
    __syncthreads();
    const int nr = t >> 3, cs = (t & 7) * 16;
    unsigned u[8];
    #pragma unroll
    for (int w = 0; w < 8; ++w)
        u[w] = (unsigned)L[nr][cs + 2 * w] | ((unsigned)L[nr][cs + 2 * w + 1] << 16);
    ushort* dst = outp + ((size_t)(b * NSP + n0 + nr)) * CD + cs;
    *(uint4*)(dst)     = make_uint4(u[0], u[1], u[2], u[3]);
    *(uint4*)(dst + 8) = make_uint4(u[4], u[5], u[6], u[7]);
}

// ---------------- MFMA q,k,v projection (all 128 o per block) ----------------
// Qt/Kt layout: [bh][n/64][d/8][n%64][8] (raw, unscaled bf16). grid 512.
__global__ __launch_bounds__(256) void proj_qkv_mfma(
    const ushort* __restrict__ Xt, const ushort* __restrict__ Ct,
    const ushort* __restrict__ Wall,
    const float* __restrict__ Bq, const float* __restrict__ Bk, const float* __restrict__ Bv,
    ushort* __restrict__ Qt, ushort* __restrict__ Kt, ushort* __restrict__ V16,
    float* __restrict__ partQ, float* __restrict__ partK)
{
    const int t = threadIdx.x;
    const int wid = t >> 6, lane = t & 63;
    const int g = lane >> 4, n16 = lane & 15;
    const int nt = blockIdx.x;
    const int b  = nt >> 8;
    const int xblk = nt & 255;
    const int nb = xblk * 16;

    const size_t xrow = ((size_t)(b * NSP + nb + n16)) * CD;
    bf16x8 bx[4], bc[4];
    #pragma unroll
    for (int ks = 0; ks < 4; ++ks) {
        bx[ks] = *(const bf16x8*)(Xt + xrow + ks * 32 + g * 8);
        bc[ks] = *(const bf16x8*)(Ct + xrow + ks * 32 + g * 8);
    }
    const int jb = nb >> 6, jr = (nb & 63) + n16;

    #pragma unroll
    for (int hf = 0; hf < 2; ++hf) {
        const int o0 = hf * 64 + wid * 16;
        const ushort* Wq = Wall          + (size_t)(o0 + n16) * CD;
        const ushort* Wk = Wall + 16384  + (size_t)(o0 + n16) * CD;
        const ushort* Wv = Wall + 32768  + (size_t)(o0 + n16) * CD;

        f32x4 aq = {0,0,0,0}, ak = {0,0,0,0}, av = {0,0,0,0};
        #pragma unroll
        for (int ks = 0; ks < 4; ++ks) {
            const int k0 = ks * 32 + g * 8;
            const bf16x8 wqf = *(const bf16x8*)(Wq + k0);
            const bf16x8 wkf = *(const bf16x8*)(Wk + k0);
            const bf16x8 wvf = *(const bf16x8*)(Wv + k0);
            aq = __builtin_amdgcn_mfma_f32_16x16x32_bf16(wqf, bx[ks], aq, 0, 0, 0);
            ak = __builtin_amdgcn_mfma_f32_16x16x32_bf16(wkf, bc[ks], ak, 0, 0, 0);
            av = __builtin_amdgcn_mfma_f32_16x16x32_bf16(wvf, bc[ks], av, 0, 0, 0);
        }
        float qv[4], kv[4], sq[4], sk[4];
        #pragma unroll
        for (int r = 0; r < 4; ++r) {
            const int o = o0 + 4 * g + r;
            qv[r] = aq[r] + Bq[o];
            kv[r] = ak[r] + Bk[o];
            V16[((size_t)(b * CD + o)) * NSP + nb + n16] = f2bf(av[r] + Bv[o]);
            sq[r] = qv[r] * qv[r]; sk[r] = kv[r] * kv[r];
        }
        {
            const int o_first = o0 + 4 * g;
            const int bh = b * NH + (o_first >> 5);
            const int chunk = ((o_first & 31) >> 3);
            const size_t idx = (((size_t)(bh * 64 + jb)) * 4 + chunk) * 512
                             + (size_t)jr * 8 + 4 * (g & 1);
            uint2 qs, ks2;
            qs.x  = pk2bf(qv[0], qv[1]); qs.y  = pk2bf(qv[2], qv[3]);
            ks2.x = pk2bf(kv[0], kv[1]); ks2.y = pk2bf(kv[2], kv[3]);
            *(uint2*)(Qt + idx) = qs;
            *(uint2*)(Kt + idx) = ks2;
        }
        #pragma unroll
        for (int r = 0; r < 4; ++r) {
            #pragma unroll
            for (int off = 1; off < 16; off <<= 1) {
                sq[r] += __shfl_xor(sq[r], off);
                sk[r] += __shfl_xor(sk[r], off);
            }
        }
        if (n16 == 0) {
            #pragma unroll
            for (int r = 0; r < 4; ++r) {
                const int ch = b * CD + o0 + 4 * g + r;
                partQ[(size_t)ch * 256 + xblk] = sq[r];
                partK[(size_t)ch * 256 + xblk] = sk[r];
            }
        }
    }
}

// ---------------- reduce norm partials -> combined per-channel factor ----------------
__global__ __launch_bounds__(256) void normfin(
    const float* __restrict__ partQ, const float* __restrict__ partK,
    float* __restrict__ fsc)
{
    const int ch = blockIdx.x;
    const int t = threadIdx.x;
    float vq = partQ[(size_t)ch * 256 + t];
    float vk = partK[(size_t)ch * 256 + t];
    #pragma unroll
    for (int off = 32; off > 0; off >>= 1) {
        vq += __shfl_down(vq, off, 64);
        vk += __shfl_down(vk, off, 64);
    }
    __shared__ float redq[4], redk[4];
    if ((t & 63) == 0) { redq[t >> 6] = vq; redk[t >> 6] = vk; }
    __syncthreads();
    if (t == 0) {
        const float nq = sqrtf(redq[0] + redq[1] + redq[2] + redq[3]);
        const float nk = sqrtf(redk[0] + redk[1] + redk[2] + redk[3]);
        fsc[ch] = QSCALE / (fmaxf(nq, 1e-12f) * fmaxf(nk, 1e-12f));
    }
}

// ---------------- MFMA flash attention partials (phase-batched) ----------------
// grid 1024, 4 waves, 32 q/wave. 4-buffer K/V rotation, counted vmcnt.
// Per step: phase A = all LDS reads + 8 QK MFMAs; B = 64 exp2 + pack; C = 8 PV MFMAs.
__global__ __launch_bounds__(256, 4) void attn_mfma(
    const ushort* __restrict__ Qt, const ushort* __restrict__ Kt,
    const ushort* __restrict__ V16, const float* __restrict__ fsc,
    unsigned* __restrict__ pacc, float* __restrict__ pl)
{
    __shared__ __align__(16) ushort Kl[4][2048];   // 16KB
    __shared__ __align__(16) ushort Vl[4][2048];   // 16KB

    const int t = threadIdx.x;
    const int wid = t >> 6, lane = t & 63;
    const int g = lane >> 4, n16 = lane & 15;
    const int f = blockIdx.x;
    const int bh = f & 7, it32 = (f >> 3) & 31, js = f >> 8;
    const int b = bh >> 2, h = bh & 3;
    const int i0 = it32 * 128 + wid * 32;

    const ushort* QtB = Qt + (size_t)bh * NSP * 32;
    const ushort* KtB = Kt + (size_t)bh * NSP * 32;
    const ushort* Vb  = V16 + (size_t)(b * CD + h * 32) * NSP;

    const float* fb = fsc + b * CD + h * 32 + g * 8;
    const f32x4 fA = *(const f32x4*)(fb);
    const f32x4 fB = *(const f32x4*)(fb + 4);

    const size_t qoff = ((size_t)(i0 >> 6) * 4 + g) * 512 + (size_t)(i0 & 63) * 8;
    const bf16x8 qr0 = *(const bf16x8*)(QtB + qoff + n16 * 8);
    const bf16x8 qr1 = *(const bf16x8*)(QtB + qoff + (16 + n16) * 8);
    auto scaleq = [&](bf16x8 q) -> bf16x8 {
        union { unsigned u[4]; bf16x8 v; } o;
        o.u[0] = pk2bf(bf2f((ushort)q[0]) * fA.x, bf2f((ushort)q[1]) * fA.y);
        o.u[1] = pk2bf(bf2f((ushort)q[2]) * fA.z, bf2f((ushort)q[3]) * fA.w);
        o.u[2] = pk2bf(bf2f((ushort)q[4]) * fB.x, bf2f((ushort)q[5]) * fB.y);
        o.u[3] = pk2bf(bf2f((ushort)q[6]) * fB.z, bf2f((ushort)q[7]) * fB.w);
        return o.v;
    };
    const bf16x8 qf[2] = { scaleq(qr0), scaleq(qr1) };

    f32x4 acc[2][2] = {{{0,0,0,0},{0,0,0,0}},{{0,0,0,0},{0,0,0,0}}};
    float l0 = 0.f, l1 = 0.f;
    const f32x4 zero = {0,0,0,0};

    const int klp = lane ^ (wid * 2);               // K source permute
    const int vd  = wid * 8 + (lane >> 3);          // V row this lane stages
    const int vsw = (lane & 7) ^ (lane >> 3);       // V 16B-chunk XOR swizzle
    auto stageK = [&](int buf, int jt) {
        gload_lds16(KtB + ((size_t)(jt >> 6) * 4 + wid) * 512 + klp * 8,
                    &Kl[buf][wid * 512]);
    };
    auto stageV = [&](int buf, int jt) {
        gload_lds16(Vb + (size_t)vd * NSP + jt + vsw * 8, &Vl[buf][wid * 512]);
    };

    const int jbeg = js * (NSP / JS);
    stageK(0, jbeg);          stageV(0, jbeg);
    stageK(1, jbeg + JSTEP);  stageV(1, jbeg + JSTEP);

    for (int step = 0; step < NSTEP; ++step) {
        const int jt = jbeg + step * JSTEP;
        if (step + 2 < NSTEP) {
            stageK((step + 2) & 3, jt + 2 * JSTEP);
            stageV((step + 2) & 3, jt + 2 * JSTEP);
            asm volatile("s_waitcnt vmcnt(4)" ::: "memory");
        } else if (step + 1 < NSTEP) {
            asm volatile("s_waitcnt vmcnt(2)" ::: "memory");
        } else {
            asm volatile("s_waitcnt vmcnt(0)" ::: "memory");
        }
        __builtin_amdgcn_s_barrier();
        const int cur = step & 3;
        __builtin_amdgcn_s_setprio(1);

        // ---- phase A: all LDS reads + all 8 QK MFMAs ----
        bf16x8 kf[2][2];
        union { uint2 u2[2]; bf16x8 v; } vf[2][2];
        #pragma unroll
        for (int s = 0; s < 2; ++s) {
            kf[s][0] = *(const bf16x8*)(&Kl[cur][g * 512 + ((s * 32 + n16) ^ (g * 2)) * 8]);
            kf[s][1] = *(const bf16x8*)(&Kl[cur][g * 512 + ((s * 32 + 16 + n16) ^ (g * 2)) * 8]);
            const int c0 = ((4 * s + (g >> 1)) ^ (n16 & 7)) * 8 + (g & 1) * 4;
            const int c1 = ((4 * s + 2 + (g >> 1)) ^ (n16 & 7)) * 8 + (g & 1) * 4;
            vf[s][0].u2[0] = *(const uint2*)(&Vl[cur][n16 * 64 + c0]);
            vf[s][0].u2[1] = *(const uint2*)(&Vl[cur][n16 * 64 + c1]);
            vf[s][1].u2[0] = *(const uint2*)(&Vl[cur][(16 + n16) * 64 + c0]);
            vf[s][1].u2[1] = *(const uint2*)(&Vl[cur][(16 + n16) * 64 + c1]);
        }
        f32x4 sv[2][2][2];
        #pragma unroll
        for (int s = 0; s < 2; ++s)
            #pragma unroll
            for (int it = 0; it < 2; ++it) {
                sv[s][it][0] = __builtin_amdgcn_mfma_f32_16x16x32_bf16(kf[s][0], qf[it], zero, 0, 0, 0);
                sv[s][it][1] = __builtin_amdgcn_mfma_f32_16x16x32_bf16(kf[s][1], qf[it], zero, 0, 0, 0);
            }

        // ---- phase B: softmax numerators ----
        union { unsigned u[4]; bf16x8 v; } pf[2][2];
        #pragma unroll
        for (int s = 0; s < 2; ++s)
            #pragma unroll
            for (int it = 0; it < 2; ++it) {
                const f32x4 s0 = sv[s][it][0], s1 = sv[s][it][1];
                const float p0 = __builtin_amdgcn_exp2f(s0.x);
                const float p1 = __builtin_amdgcn_exp2f(s0.y);
                const float p2 = __builtin_amdgcn_exp2f(s0.z);
                const float p3 = __builtin_amdgcn_exp2f(s0.w);
                const float p4 = __builtin_amdgcn_exp2f(s1.x);
                const float p5 = __builtin_amdgcn_exp2f(s1.y);
                const float p6 = __builtin_amdgcn_exp2f(s1.z);
                const float p7 = __builtin_amdgcn_exp2f(s1.w);
                const float ps = ((p0 + p1) + (p2 + p3)) + ((p4 + p5) + (p6 + p7));
                if (it) l1 += ps; else l0 += ps;
                pf[s][it].u[0] = pk2bf(p0, p1);
                pf[s][it].u[1] = pk2bf(p2, p3);
                pf[s][it].u[2] = pk2bf(p4, p5);
                pf[s][it].u[3] = pk2bf(p6, p7);
            }

        // ---- phase C: all 8 PV MFMAs ----
        #pragma unroll
        for (int s = 0; s < 2; ++s)
            #pragma unroll
            for (int it = 0; it < 2; ++it) {
                acc[it][0] = __builtin_amdgcn_mfma_f32_16x16x32_bf16(vf[s][0].v, pf[s][it].v, acc[it][0], 0, 0, 0);
                acc[it][1] = __builtin_amdgcn_mfma_f32_16x16x32_bf16(vf[s][1].v, pf[s][it].v, acc[it][1], 0, 0, 0);
            }
        __builtin_amdgcn_s_setprio(0);
    }

    l0 += __shfl_xor(l0, 16); l0 += __shfl_xor(l0, 32);
    l1 += __shfl_xor(l1, 16); l1 += __shfl_xor(l1, 32);

    const size_t base = (size_t)js * 8 + bh;
    if (lane < 16) {
        pl[base * NSP + i0 + n16]      = l0;
        pl[base * NSP + i0 + 16 + n16] = l1;
    }
    unsigned* pb = pacc + base * 16 * NSP;
    const int col0 = i0 + n16, col1 = i0 + 16 + n16;
    pb[(size_t)(2 * g)     * NSP + col0] = pk2bf(acc[0][0][0], acc[0][0][1]);
    pb[(size_t)(2 * g + 1) * NSP + col0] = pk2bf(acc[0][0][2], acc[0][0][3]);
    pb[(size_t)(8 + 2 * g)     * NSP + col0] = pk2bf(acc[0][1][0], acc[0][1][1]);
    pb[(size_t)(8 + 2 * g + 1) * NSP + col0] = pk2bf(acc[0][1][2], acc[0][1][3]);
    pb[(size_t)(2 * g)     * NSP + col1] = pk2bf(acc[1][0][0], acc[1][0][1]);
    pb[(size_t)(2 * g + 1) * NSP + col1] = pk2bf(acc[1][0][2], acc[1][0][3]);
    pb[(size_t)(8 + 2 * g)     * NSP + col1] = pk2bf(acc[1][1][0], acc[1][1][1]);
    pb[(size_t)(8 + 2 * g + 1) * NSP + col1] = pk2bf(acc[1][1][2], acc[1][1][3]);
}

// ---------------- fused combine + output projection ----------------
__global__ __launch_bounds__(256) void combine_proj_out(
    const unsigned* __restrict__ pacc, const float* __restrict__ pl,
    const ushort* __restrict__ Wall, const float* __restrict__ Bo,
    float* __restrict__ outp)
{
    __shared__ __align__(16) ushort Yl[16][128];
    const int t = threadIdx.x;
    const int nt = blockIdx.x;
    const int b  = nt >> 8;
    const int nb = (nt & 255) * 16;

    {
        const int nl = t & 15, hh = (t >> 4) & 3, q = t >> 6;
        const int bh = b * NH + hh;
        const int n = nb + nl;
        float L = 0.f;
        #pragma unroll
        for (int s = 0; s < JS; ++s) L += pl[((size_t)(s * 8 + bh)) * NSP + n];
        const float invL = 1.0f / L;
        unsigned u[4];
        #pragma unroll
        for (int e = 0; e < 4; ++e) {
            const int dp = q * 4 + e;
            float a0 = 0.f, a1 = 0.f;
            #pragma unroll
            for (int s = 0; s < JS; ++s) {
                const unsigned w = pacc[(((size_t)(s * 8 + bh)) * 16 + dp) * NSP + n];
                union { unsigned u; float f; } lo, hi;
                lo.u = w << 16; hi.u = w & 0xffff0000u;
                a0 += lo.f; a1 += hi.f;
            }
            u[e] = pk2bf(a0 * invL, a1 * invL);
        }
        const int chunk = hh * 4 + q;
        *(uint4*)(&Yl[nl][((chunk ^ (nl & 7)) * 8)]) = make_uint4(u[0], u[1], u[2], u[3]);
    }
    __syncthreads();

    const int wid = t >> 6, lane = t & 63;
    const int g = lane >> 4, n16 = lane & 15;
    const ushort* Wo = Wall + 49152;
    #pragma unroll
    for (int half = 0; half < 2; ++half) {
        const int o0 = half * 64 + wid * 16;
        const size_t wrow = (size_t)(o0 + n16) * CD;
        f32x4 a = {0,0,0,0};
        #pragma unroll
        for (int ks = 0; ks < 4; ++ks) {
            const bf16x8 wf = *(const bf16x8*)(Wo + wrow + ks * 32 + g * 8);
            const int chunk = ks * 4 + g;
            const bf16x8 yf = *(const bf16x8*)(&Yl[n16][((chunk ^ (n16 & 7)) * 8)]);
            a = __builtin_amdgcn_mfma_f32_16x16x32_bf16(wf, yf, a, 0, 0, 0);
        }
        #pragma unroll
        for (int r = 0; r < 4; ++r) {
            const int o = o0 + 4 * g + r;
            outp[((size_t)(b * CD + o)) * NSP + nb + n16] = a[r] + Bo[o];
        }
    }
}

extern "C" void kernel_launch(void* const* d_in, const int* in_sizes, int n_in,
                              void* d_out, int out_size, void* d_ws, size_t ws_size,
                              hipStream_t stream)
{
    const float* x  = (const float*)d_in[0];
    const float* cx = (const float*)d_in[1];
    const float* Wq = (const float*)d_in[2];
    const float* bq = (const float*)d_in[3];
    const float* Wk = (const float*)d_in[4];
    const float* bk = (const float*)d_in[5];
    const float* Wv = (const float*)d_in[6];
    const float* bv = (const float*)d_in[7];
    const float* Wo = (const float*)d_in[8];
    const float* bo = (const float*)d_in[9];
    float* out = (float*)d_out;

    char* w = (char*)d_ws;
    float*   fsc  = (float*)w;   w += 4096;
    float*   partQ = (float*)w;  w += (size_t)NB * CD * 256 * 4;        // 256 KB
    float*   partK = (float*)w;  w += (size_t)NB * CD * 256 * 4;        // 256 KB
    ushort*  Qt   = (ushort*)w;  w += (size_t)NB * NH * NSP * 32 * 2;   // 2 MB
    ushort*  Kt   = (ushort*)w;  w += (size_t)NB * NH * NSP * 32 * 2;   // 2 MB
    ushort*  V16  = (ushort*)w;  w += (size_t)NB * CD * NSP * 2;        // 2 MB
    unsigned* pacc = (unsigned*)w; w += (size_t)JS * 8 * 16 * NSP * 4;  // 8 MB
    float*   pl   = (float*)w;   w += (size_t)JS * 8 * NSP * 4;         // 512 KB
    ushort*  Xt   = (ushort*)w;  w += (size_t)NB * NSP * CD * 2;        // 2 MB
    ushort*  Ct   = (ushort*)w;  w += (size_t)NB * NSP * CD * 2;        // 2 MB
    ushort*  Wall = (ushort*)w;                                         // 128 KB

    cast_all<<<dim3(144, NB, 2), 256, 0, stream>>>(x, cx, Wq, Wk, Wv, Wo, Xt, Ct, Wall);
    proj_qkv_mfma<<<dim3(512), 256, 0, stream>>>(Xt, Ct, Wall, bq, bk, bv,
                                                 Qt, Kt, V16, partQ, partK);
    normfin<<<dim3(256), 256, 0, stream>>>(partQ, partK, fsc);
    attn_mfma<<<dim3(1024), 256, 0, stream>>>(Qt, Kt, V16, fsc, pacc, pl);
    combine_proj_out<<<dim3(512), 256, 0, stream>>>(pacc, pl, Wall, bo, out);
}